// Round 8
// baseline (3909.387 us; speedup 1.0000x reference)
//
#include <hip/hip_runtime.h>

#define DIMD 256
#define SEQT 1024
#define NB   4
#define KBS  20   // 16-float row block + 4 pad: rg*20 mod 32 spreads banks, 16B-aligned stage writes

typedef float v2f __attribute__((ext_vector_type(2)));

// Forced packed fp32 math (gfx950 V_PK_*): "v" on an 8-byte value = VGPR pair.
__device__ __forceinline__ v2f pk_mul(v2f a, v2f b){
  v2f d; asm("v_pk_mul_f32 %0, %1, %2" : "=v"(d) : "v"(a), "v"(b)); return d;
}
__device__ __forceinline__ v2f pk_fma(v2f a, v2f b, v2f c){
  v2f d; asm("v_pk_fma_f32 %0, %1, %2, %3" : "=v"(d) : "v"(a), "v"(b), "v"(c)); return d;
}

__device__ __forceinline__ float sigmoidf_(float x){ return 1.0f/(1.0f+expf(-x)); }

// ---------------------------------------------------------------------------
// GEMM: C[m][n] = sum_k A[m][k] * B[n][k], K = 256 fixed, tiles 64x64.
// EPI==1: C *= sigmoid(gpre[m*N+n])
// ---------------------------------------------------------------------------
template<int EPI>
__global__ __launch_bounds__(256) void gemm_bt(const float* __restrict__ A,
    const float* __restrict__ Bm, float* __restrict__ C, int N,
    const float* __restrict__ gpre)
{
  __shared__ float sA[64][68];
  __shared__ float sB[64][68];
  const int nb = N >> 6;
  const int bm = blockIdx.x / nb, bn = blockIdx.x - bm*nb;
  const int m0 = bm << 6, n0 = bn << 6;
  const int tid = threadIdx.x;
  const int tr = tid >> 4, tc = tid & 15;
  float acc[4][4];
  #pragma unroll
  for (int i=0;i<4;i++)
    #pragma unroll
    for (int j=0;j<4;j++) acc[i][j]=0.f;

  for (int kc=0;kc<4;kc++){
    __syncthreads();
    for (int i=tid;i<1024;i+=256){
      int r = i >> 4, q4 = i & 15;
      *(float4*)&sA[r][q4*4] = ((const float4*)(A  + (m0+r)*256 + kc*64))[q4];
      *(float4*)&sB[r][q4*4] = ((const float4*)(Bm + (n0+r)*256 + kc*64))[q4];
    }
    __syncthreads();
    #pragma unroll
    for (int kq=0;kq<16;kq++){
      float4 av[4], bv[4];
      #pragma unroll
      for (int i=0;i<4;i++) av[i] = *(const float4*)&sA[tr+16*i][kq*4];
      #pragma unroll
      for (int j=0;j<4;j++) bv[j] = *(const float4*)&sB[tc+16*j][kq*4];
      #pragma unroll
      for (int i=0;i<4;i++)
        #pragma unroll
        for (int j=0;j<4;j++)
          acc[i][j] = fmaf(av[i].x,bv[j].x, fmaf(av[i].y,bv[j].y,
                      fmaf(av[i].z,bv[j].z, fmaf(av[i].w,bv[j].w, acc[i][j]))));
    }
  }
  #pragma unroll
  for (int i=0;i<4;i++){
    #pragma unroll
    for (int j=0;j<4;j++){
      int m = m0 + tr + 16*i, n = n0 + tc + 16*j;
      float val = acc[i][j];
      if (EPI==1) val *= sigmoidf_(gpre[m*N+n]);
      C[m*N+n] = val;
    }
  }
}

// ---------------------------------------------------------------------------
// prep: causal dwconv(4) + RoPE + l2norm for q,k ; conv for v ; eta/alpha.
// ---------------------------------------------------------------------------
__global__ __launch_bounds__(256) void prep_kernel(
    const float* __restrict__ qkvr, const float* __restrict__ x,
    const float* __restrict__ cosT, const float* __restrict__ sinT,
    const float* __restrict__ qw, const float* __restrict__ qbias,
    const float* __restrict__ kw, const float* __restrict__ kbias,
    const float* __restrict__ vw, const float* __restrict__ vbias,
    const float* __restrict__ Wparam, const float* __restrict__ bparam,
    float* __restrict__ qo, float* __restrict__ ko, float* __restrict__ vo,
    float* __restrict__ eo, float* __restrict__ ao)
{
  const int bt = blockIdx.x;
  const int t = bt & 1023;
  const int d = threadIdx.x;

  float4 wq = ((const float4*)qw)[d];
  float4 wk = ((const float4*)kw)[d];
  float4 wv = ((const float4*)vw)[d];
  const float wqj[4] = {wq.x,wq.y,wq.z,wq.w};
  const float wkj[4] = {wk.x,wk.y,wk.z,wk.w};
  const float wvj[4] = {wv.x,wv.y,wv.z,wv.w};
  float qa = qbias[d], ka = kbias[d], va = vbias[d];
  #pragma unroll
  for (int j=0;j<4;j++){
    int tt = t - 3 + j;
    if (tt >= 0) {
      const float* row = qkvr + (size_t)(bt - 3 + j) * 768;
      qa = fmaf(row[d],      wqj[j], qa);
      ka = fmaf(row[256+d],  wkj[j], ka);
      va = fmaf(row[512+d],  wvj[j], va);
    }
  }
  vo[bt*256 + d] = va;

  __shared__ float sq[256], sk[256];
  __shared__ float red[4][4];
  sq[d] = qa; sk[d] = ka;
  __syncthreads();
  const int i = d >> 1;
  const float c = cosT[t*128 + i], s = sinT[t*128 + i];
  float qr, krp;
  if ((d & 1) == 0) { qr = sq[d]*c - sq[d+1]*s;  krp = sk[d]*c - sk[d+1]*s; }
  else              { qr = sq[d-1]*s + sq[d]*c;  krp = sk[d-1]*s + sk[d]*c; }

  const float xd = x[bt*256 + d];
  float r0 = qr*qr, r1 = krp*krp, r2 = xd*Wparam[d], r3 = xd*Wparam[256+d];
  #pragma unroll
  for (int m=1;m<64;m<<=1){
    r0 += __shfl_xor(r0, m, 64);
    r1 += __shfl_xor(r1, m, 64);
    r2 += __shfl_xor(r2, m, 64);
    r3 += __shfl_xor(r3, m, 64);
  }
  const int w = d >> 6;
  if ((d & 63) == 0){ red[w][0]=r0; red[w][1]=r1; red[w][2]=r2; red[w][3]=r3; }
  __syncthreads();
  float qss = red[0][0]+red[1][0]+red[2][0]+red[3][0];
  float kss = red[0][1]+red[1][1]+red[2][1]+red[3][1];
  qo[bt*256+d] = qr  / fmaxf(sqrtf(qss), 1e-12f);
  ko[bt*256+d] = krp / fmaxf(sqrtf(kss), 1e-12f);
  if (d == 0){
    float p0 = red[0][2]+red[1][2]+red[2][2]+red[3][2] + bparam[0];
    float p1 = red[0][3]+red[1][3]+red[2][3]+red[3][3] + bparam[1];
    eo[bt] = 1.f/(1.f+expf(-p0));
    ao[bt] = 1.f/(1.f+expf(-p1));
  }
}

// ---------------------------------------------------------------------------
// scan: one block per batch, 1024 threads (4 waves/SIMD), ONE barrier/step.
// Thread (rg=tid&15, cg=tid>>4) owns rows 16rg..16rg+15, cols 4cg..4cg+3.
// ROWS are packed into v2f lanes: A2[rp*4+ci] = {A[r0+2rp][c0+ci],
// A[r0+2rp+1][c0+ci]}. k/q/k_next are read from LDS directly as v2f
// row-pairs (no broadcast, no repack); the only broadcasts are 5 per-step
// v2f constants ({-t0[ci]} x4, {al}). All hot-loop math is inline-asm
// v_pk_fma_f32 / v_pk_mul_f32 -- forces packed issue AND arch-VGPR
// residency for A2 (AGPRs can't feed v_pk_*).
// k/q LDS layout: 16-float row blocks at stride KBS=20 -> v2f read bank-words
// rg*20+rp*2 mod 32 spread over 8+ values (worst 2-way alias = free, m136);
// float4 stage writes at rg*80B stay 16B-aligned.
// Triple-buffered k/q/v/ea; double-buffered s_s4; cross-rg reduces are
// intra-wave shuffles (rg = tid&15 spans 16 adjacent lanes).
// ---------------------------------------------------------------------------
__global__ __launch_bounds__(1024, 4) void scan_kernel(
    const float* __restrict__ qn, const float* __restrict__ kn,
    const float* __restrict__ vn, const float* __restrict__ eta,
    const float* __restrict__ alpha, const float* __restrict__ W0,
    float* __restrict__ y)
{
  const int b = blockIdx.x;
  const int tid = threadIdx.x;
  const int rg = tid & 15;        // row group: rows 16*rg .. 16*rg+15
  const int cg = tid >> 4;        // col group: cols 4*cg .. 4*cg+3
  const int r0 = rg << 4;
  const int c0 = cg << 2;
  const int koff = rg * KBS;      // staggered base of this row block

  __shared__ float s_k[3][16*KBS], s_q[3][16*KBS], s_v[3][256];
  __shared__ float s_ea[3][2];
  __shared__ float s_s4[2][16];

  // A2[4*rp+ci] = {A[r0+2rp][c0+ci], A[r0+2rp+1][c0+ci]}
  v2f A2[32];
  #pragma unroll
  for (int j=0;j<32;j++) A2[j] = (v2f)(0.f);

  const float* kb = kn + b*SEQT*DIMD;
  const float* qb = qn + b*SEQT*DIMD;
  const float* vb = vn + b*SEQT*DIMD;
  const float* eb = eta   + b*SEQT;
  const float* ab = alpha + b*SEQT;
  float* yb = y + b*SEQT*DIMD;

  // ---- prologue: stage t=0 -> buf0 ; load t=1 into pf regs
  if (tid < 64) {
    float4 v0 = ((const float4*)kb)[tid];
    *(float4*)&s_k[0][(tid>>2)*KBS + (tid&3)*4] = v0;
  } else if (tid < 128) {
    int i = tid-64;
    float4 v0 = ((const float4*)qb)[i];
    *(float4*)&s_q[0][(i>>2)*KBS + (i&3)*4] = v0;
  } else if (tid < 192) {
    ((float4*)s_v[0])[tid-128] = ((const float4*)vb)[tid-128];
  }
  if (tid == 192) { s_ea[0][0] = eb[0]; s_ea[0][1] = ab[0]; }

  float4 pf = make_float4(0.f,0.f,0.f,0.f);
  float pe = 0.f, pa = 0.f;
  if (tid < 64)       pf = ((const float4*)(kb + DIMD))[tid];
  else if (tid < 128) pf = ((const float4*)(qb + DIMD))[tid-64];
  else if (tid < 192) pf = ((const float4*)(vb + DIMD))[tid-128];
  if (tid == 192) { pe = eb[1]; pa = ab[1]; }
  __syncthreads();

  // ---- prologue: pred_raw(0) = k(0) . W0 partial over own rows/cols
  float pr4[4] = {0.f,0.f,0.f,0.f};
  {
    #pragma unroll 4
    for (int j=0;j<16;j++){
      float ks = s_k[0][koff + j];
      float4 w4 = *(const float4*)(W0 + (size_t)(r0+j)*DIMD + c0);
      pr4[0] = fmaf(ks, w4.x, pr4[0]);
      pr4[1] = fmaf(ks, w4.y, pr4[1]);
      pr4[2] = fmaf(ks, w4.z, pr4[2]);
      pr4[3] = fmaf(ks, w4.w, pr4[3]);
    }
    #pragma unroll
    for (int m=1;m<16;m<<=1){
      pr4[0] += __shfl_xor(pr4[0], m, 64);
      pr4[1] += __shfl_xor(pr4[1], m, 64);
      pr4[2] += __shfl_xor(pr4[2], m, 64);
      pr4[3] += __shfl_xor(pr4[3], m, 64);
    }
  }

  float up4[4] = {0.f,0.f,0.f,0.f};   // u of step t-1 (deferred y write)
  int cur = 0;

  for (int t=0; t<SEQT; ++t) {
    const int nxt = (cur==2) ? 0 : cur+1;

    // ---- stage pf (t+1 data) -> buf nxt
    if (t+1 < SEQT) {
      if (tid < 64)       *(float4*)&s_k[nxt][(tid>>2)*KBS + (tid&3)*4] = pf;
      else if (tid < 128){ int i = tid-64; *(float4*)&s_q[nxt][(i>>2)*KBS + (i&3)*4] = pf; }
      else if (tid < 192) ((float4*)s_v[nxt])[tid-128] = pf;
      if (tid == 192) { s_ea[nxt][0]=pe; s_ea[nxt][1]=pa; }
    }

    __syncthreads();                               // the ONE barrier

    // ---- issue global prefetch for t+2 (lands under the fused loop)
    if (t+2 < SEQT) {
      if (tid < 64)       pf = ((const float4*)(kb + (t+2)*DIMD))[tid];
      else if (tid < 128) pf = ((const float4*)(qb + (t+2)*DIMD))[tid-64];
      else if (tid < 192) pf = ((const float4*)(vb + (t+2)*DIMD))[tid-128];
      if (tid == 192) { pe = eb[t+2]; pa = ab[t+2]; }
    }

    // ---- inv(t-1) from s4 partials ; deferred y(t-1) write
    float scale = 1.f;
    if (t > 0) {
      const float* sp = s_s4[(t-1)&1];
      float4 sa = ((const float4*)sp)[0], sb4 = ((const float4*)sp)[1];
      float4 sc4= ((const float4*)sp)[2], sd4 = ((const float4*)sp)[3];
      float s4t = ((sa.x+sa.y)+(sa.z+sa.w)) + ((sb4.x+sb4.y)+(sb4.z+sb4.w))
                + ((sc4.x+sc4.y)+(sc4.z+sc4.w)) + ((sd4.x+sd4.y)+(sd4.z+sd4.w));
      float w = sqrtf(s4t) + 1e-6f;
      float r = __builtin_amdgcn_rcpf(w);
      r = r * (2.f - w*r);          // Newton: feeds the recurrence
      scale = r;
      if (rg == 0) {
        float4 yo = make_float4(up4[0]*r, up4[1]*r, up4[2]*r, up4[3]*r);
        *(float4*)(yb + (size_t)(t-1)*DIMD + c0) = yo;
      }
    }

    // ---- per-column t0 and packed broadcast constants
    const float et = s_ea[cur][0], al = s_ea[cur][1];
    float4 v4 = *(const float4*)(s_v[cur] + c0);
    const float vv[4] = {v4.x, v4.y, v4.z, v4.w};
    v2f nt0b[4];
    #pragma unroll
    for (int ci=0; ci<4; ++ci){
      float pred = pr4[ci] * scale;
      float df = pred - vv[ci];
      float e  = __expf(20.f*df);                       // tanh(10df)=1-2/(e+1)
      float th = 1.f - 2.f*__builtin_amdgcn_rcpf(e + 1.f);
      float t0 = et * 3.f * th * (df*df);
      float nt0 = -t0;
      nt0b[ci].x = nt0; nt0b[ci].y = nt0;
    }
    v2f alb; alb.x = al; alb.y = al;

    // ---- fused: A update + sumA^4 + q-dot + NEXT k-dot (all forced-packed)
    const v2f* kp = (const v2f*)(s_k[cur] + koff);   // {k[r0+2i], k[r0+2i+1]}
    const v2f* qp = (const v2f*)(s_q[cur] + koff);
    const v2f* np = (const v2f*)(s_k[nxt] + koff);   // k(t+1)
    v2f s4a = (v2f)(0.f), s4b = (v2f)(0.f);
    v2f uc0=(v2f)(0.f), uc1=(v2f)(0.f), uc2=(v2f)(0.f), uc3=(v2f)(0.f);
    v2f pc0=(v2f)(0.f), pc1=(v2f)(0.f), pc2=(v2f)(0.f), pc3=(v2f)(0.f);
    #pragma unroll
    for (int rp=0; rp<8; ++rp){
      v2f kv = kp[rp], qv = qp[rp], nv = np[rp];
      v2f a0 = pk_fma(alb, A2[4*rp+0], pk_mul(nt0b[0], kv)); A2[4*rp+0] = a0;
      v2f a1 = pk_fma(alb, A2[4*rp+1], pk_mul(nt0b[1], kv)); A2[4*rp+1] = a1;
      v2f a2 = pk_fma(alb, A2[4*rp+2], pk_mul(nt0b[2], kv)); A2[4*rp+2] = a2;
      v2f a3 = pk_fma(alb, A2[4*rp+3], pk_mul(nt0b[3], kv)); A2[4*rp+3] = a3;
      v2f q0 = pk_mul(a0,a0), q1 = pk_mul(a1,a1);
      v2f q2 = pk_mul(a2,a2), q3 = pk_mul(a3,a3);
      s4a = pk_fma(q0,q0,s4a); s4b = pk_fma(q1,q1,s4b);
      s4a = pk_fma(q2,q2,s4a); s4b = pk_fma(q3,q3,s4b);
      uc0 = pk_fma(qv,a0,uc0); uc1 = pk_fma(qv,a1,uc1);
      uc2 = pk_fma(qv,a2,uc2); uc3 = pk_fma(qv,a3,uc3);
      pc0 = pk_fma(nv,a0,pc0); pc1 = pk_fma(nv,a1,pc1);
      pc2 = pk_fma(nv,a2,pc2); pc3 = pk_fma(nv,a3,pc3);
    }

    // ---- horizontal + intra-wave cross-rg reduce (lanes xor 1,2,4,8)
    float red8[8];
    red8[0] = uc0.x + uc0.y; red8[1] = uc1.x + uc1.y;
    red8[2] = uc2.x + uc2.y; red8[3] = uc3.x + uc3.y;
    red8[4] = pc0.x + pc0.y; red8[5] = pc1.x + pc1.y;
    red8[6] = pc2.x + pc2.y; red8[7] = pc3.x + pc3.y;
    #pragma unroll
    for (int m=1;m<16;m<<=1){
      #pragma unroll
      for (int i=0;i<8;i++) red8[i] += __shfl_xor(red8[i], m, 64);
    }
    up4[0]=red8[0]; up4[1]=red8[1]; up4[2]=red8[2]; up4[3]=red8[3];
    pr4[0]=red8[4]; pr4[1]=red8[5]; pr4[2]=red8[6]; pr4[3]=red8[7];

    // ---- s4 wave reduce -> per-wave slot (consumed next step post-barrier)
    float s4 = (s4a.x + s4a.y) + (s4b.x + s4b.y);
    #pragma unroll
    for (int m=1;m<64;m<<=1) s4 += __shfl_xor(s4, m, 64);
    if ((tid & 63) == 0) s_s4[t&1][tid>>6] = s4;

    cur = nxt;
  }

  __syncthreads();
  // epilogue: y for t = 1023 (s4 in s_s4[1023&1 = 1])
  {
    const float* sp = s_s4[1];
    float4 sa = ((const float4*)sp)[0], sb4 = ((const float4*)sp)[1];
    float4 sc4= ((const float4*)sp)[2], sd4 = ((const float4*)sp)[3];
    float s4t = ((sa.x+sa.y)+(sa.z+sa.w)) + ((sb4.x+sb4.y)+(sb4.z+sb4.w))
              + ((sc4.x+sc4.y)+(sc4.z+sc4.w)) + ((sd4.x+sd4.y)+(sd4.z+sd4.w));
    float w = sqrtf(s4t) + 1e-6f;
    float r = __builtin_amdgcn_rcpf(w);
    r = r * (2.f - w*r);
    if (rg == 0) {
      float4 yo = make_float4(up4[0]*r, up4[1]*r, up4[2]*r, up4[3]*r);
      *(float4*)(yb + (size_t)1023*DIMD + c0) = yo;
    }
  }
}

// ---------------------------------------------------------------------------
extern "C" void kernel_launch(void* const* d_in, const int* in_sizes, int n_in,
                              void* d_out, int out_size, void* d_ws, size_t ws_size,
                              hipStream_t stream)
{
  const float* x     = (const float*)d_in[0];
  const float* cosT  = (const float*)d_in[1];
  const float* sinT  = (const float*)d_in[2];
  const float* Wqkv  = (const float*)d_in[3];
  const float* qw    = (const float*)d_in[4];
  const float* qb    = (const float*)d_in[5];
  const float* kw    = (const float*)d_in[6];
  const float* kb    = (const float*)d_in[7];
  const float* vw    = (const float*)d_in[8];
  const float* vb    = (const float*)d_in[9];
  const float* Wparam= (const float*)d_in[10];
  const float* bparam= (const float*)d_in[11];
  const float* W0    = (const float*)d_in[12];
  const float* Wgate = (const float*)d_in[13];
  const float* Wout  = (const float*)d_in[14];
  float* out = (float*)d_out;

  float* ws    = (float*)d_ws;
  float* qkvr  = ws;                         // 4*1024*768  = 3,145,728 f
  float* qn    = qkvr + 4*1024*768;          // 1,048,576 f
  float* kn    = qn   + 4*1024*256;
  float* vn    = kn   + 4*1024*256;
  float* eta   = vn   + 4*1024*256;          // 4096 f
  float* alpha = eta  + 4096;                // 4096 f
  // qkvr is dead after prep_kernel -> reuse its space:
  float* yv    = qkvr;                       // scan output  (1,048,576 f)
  float* tmpg  = qkvr + 1048576;             // gate preact  (1,048,576 f)

  // 1) qkv = x @ Wqkv.T          (4096 x 768)
  gemm_bt<0><<<dim3(64*12), 256, 0, stream>>>(x, Wqkv, qkvr, 768, nullptr);
  // 2) conv + rope + l2norm + eta/alpha
  prep_kernel<<<dim3(4096), 256, 0, stream>>>(qkvr, x, cosT, sinT,
      qw, qb, kw, kb, vw, vb, Wparam, bparam, qn, kn, vn, eta, alpha);
  // 3) the sequential scan (one block per batch)
  scan_kernel<<<dim3(NB), 1024, 0, stream>>>(qn, kn, vn, eta, alpha, W0, yv);
  // 4) gate preact = x @ Wgate.T (4096 x 256)
  gemm_bt<0><<<dim3(64*4), 256, 0, stream>>>(x, Wgate, tmpg, 256, nullptr);
  // 5) out = (y @ Wout.T) * sigmoid(gate)
  gemm_bt<1><<<dim3(64*4), 256, 0, stream>>>(yv, Wout, out, 256, tmpg);
}

// Round 9
// 3130.585 us; speedup vs baseline: 1.2488x; 1.2488x over previous
//
#include <hip/hip_runtime.h>

#define DIMD 256
#define SEQT 1024
#define NB   4
#define RBS  36   // 32-row block + 4 pad: read bank-words 4*rg+4*j distinct -> conflict-free

typedef float v2f __attribute__((ext_vector_type(2)));
#define FMA2(a,b,c) __builtin_elementwise_fma((a),(b),(c))

__device__ __forceinline__ float sigmoidf_(float x){ return 1.0f/(1.0f+expf(-x)); }

// ---------------------------------------------------------------------------
// GEMM: C[m][n] = sum_k A[m][k] * B[n][k], K = 256 fixed, tiles 64x64.
// EPI==1: C *= sigmoid(gpre[m*N+n])
// ---------------------------------------------------------------------------
template<int EPI>
__global__ __launch_bounds__(256) void gemm_bt(const float* __restrict__ A,
    const float* __restrict__ Bm, float* __restrict__ C, int N,
    const float* __restrict__ gpre)
{
  __shared__ float sA[64][68];
  __shared__ float sB[64][68];
  const int nb = N >> 6;
  const int bm = blockIdx.x / nb, bn = blockIdx.x - bm*nb;
  const int m0 = bm << 6, n0 = bn << 6;
  const int tid = threadIdx.x;
  const int tr = tid >> 4, tc = tid & 15;
  float acc[4][4];
  #pragma unroll
  for (int i=0;i<4;i++)
    #pragma unroll
    for (int j=0;j<4;j++) acc[i][j]=0.f;

  for (int kc=0;kc<4;kc++){
    __syncthreads();
    for (int i=tid;i<1024;i+=256){
      int r = i >> 4, q4 = i & 15;
      *(float4*)&sA[r][q4*4] = ((const float4*)(A  + (m0+r)*256 + kc*64))[q4];
      *(float4*)&sB[r][q4*4] = ((const float4*)(Bm + (n0+r)*256 + kc*64))[q4];
    }
    __syncthreads();
    #pragma unroll
    for (int kq=0;kq<16;kq++){
      float4 av[4], bv[4];
      #pragma unroll
      for (int i=0;i<4;i++) av[i] = *(const float4*)&sA[tr+16*i][kq*4];
      #pragma unroll
      for (int j=0;j<4;j++) bv[j] = *(const float4*)&sB[tc+16*j][kq*4];
      #pragma unroll
      for (int i=0;i<4;i++)
        #pragma unroll
        for (int j=0;j<4;j++)
          acc[i][j] = fmaf(av[i].x,bv[j].x, fmaf(av[i].y,bv[j].y,
                      fmaf(av[i].z,bv[j].z, fmaf(av[i].w,bv[j].w, acc[i][j]))));
    }
  }
  #pragma unroll
  for (int i=0;i<4;i++){
    #pragma unroll
    for (int j=0;j<4;j++){
      int m = m0 + tr + 16*i, n = n0 + tc + 16*j;
      float val = acc[i][j];
      if (EPI==1) val *= sigmoidf_(gpre[m*N+n]);
      C[m*N+n] = val;
    }
  }
}

// ---------------------------------------------------------------------------
// prep: causal dwconv(4) + RoPE + l2norm for q,k ; conv for v ; eta/alpha.
// ---------------------------------------------------------------------------
__global__ __launch_bounds__(256) void prep_kernel(
    const float* __restrict__ qkvr, const float* __restrict__ x,
    const float* __restrict__ cosT, const float* __restrict__ sinT,
    const float* __restrict__ qw, const float* __restrict__ qbias,
    const float* __restrict__ kw, const float* __restrict__ kbias,
    const float* __restrict__ vw, const float* __restrict__ vbias,
    const float* __restrict__ Wparam, const float* __restrict__ bparam,
    float* __restrict__ qo, float* __restrict__ ko, float* __restrict__ vo,
    float* __restrict__ eo, float* __restrict__ ao)
{
  const int bt = blockIdx.x;
  const int t = bt & 1023;
  const int d = threadIdx.x;

  float4 wq = ((const float4*)qw)[d];
  float4 wk = ((const float4*)kw)[d];
  float4 wv = ((const float4*)vw)[d];
  const float wqj[4] = {wq.x,wq.y,wq.z,wq.w};
  const float wkj[4] = {wk.x,wk.y,wk.z,wk.w};
  const float wvj[4] = {wv.x,wv.y,wv.z,wv.w};
  float qa = qbias[d], ka = kbias[d], va = vbias[d];
  #pragma unroll
  for (int j=0;j<4;j++){
    int tt = t - 3 + j;
    if (tt >= 0) {
      const float* row = qkvr + (size_t)(bt - 3 + j) * 768;
      qa = fmaf(row[d],      wqj[j], qa);
      ka = fmaf(row[256+d],  wkj[j], ka);
      va = fmaf(row[512+d],  wvj[j], va);
    }
  }
  vo[bt*256 + d] = va;

  __shared__ float sq[256], sk[256];
  __shared__ float red[4][4];
  sq[d] = qa; sk[d] = ka;
  __syncthreads();
  const int i = d >> 1;
  const float c = cosT[t*128 + i], s = sinT[t*128 + i];
  float qr, krp;
  if ((d & 1) == 0) { qr = sq[d]*c - sq[d+1]*s;  krp = sk[d]*c - sk[d+1]*s; }
  else              { qr = sq[d-1]*s + sq[d]*c;  krp = sk[d-1]*s + sk[d]*c; }

  const float xd = x[bt*256 + d];
  float r0 = qr*qr, r1 = krp*krp, r2 = xd*Wparam[d], r3 = xd*Wparam[256+d];
  #pragma unroll
  for (int m=1;m<64;m<<=1){
    r0 += __shfl_xor(r0, m, 64);
    r1 += __shfl_xor(r1, m, 64);
    r2 += __shfl_xor(r2, m, 64);
    r3 += __shfl_xor(r3, m, 64);
  }
  const int w = d >> 6;
  if ((d & 63) == 0){ red[w][0]=r0; red[w][1]=r1; red[w][2]=r2; red[w][3]=r3; }
  __syncthreads();
  float qss = red[0][0]+red[1][0]+red[2][0]+red[3][0];
  float kss = red[0][1]+red[1][1]+red[2][1]+red[3][1];
  qo[bt*256+d] = qr  / fmaxf(sqrtf(qss), 1e-12f);
  ko[bt*256+d] = krp / fmaxf(sqrtf(kss), 1e-12f);
  if (d == 0){
    float p0 = red[0][2]+red[1][2]+red[2][2]+red[3][2] + bparam[0];
    float p1 = red[0][3]+red[1][3]+red[2][3]+red[3][3] + bparam[1];
    eo[bt] = 1.f/(1.f+expf(-p0));
    ao[bt] = 1.f/(1.f+expf(-p1));
  }
}

// ---------------------------------------------------------------------------
// scan: TWO blocks per batch (8 blocks total), 1024 threads each, one
// barrier/step. Block h owns columns h*128..h*128+127; the only cross-block
// quantity is the scalar sumA^4, consumed with one-step delay -> exchanged
// through global memory (agent-scope release store / acquire spin-load on
// a 0xAA-poisoned slot; sum of quartics >= 0 can never equal the poison).
// Thread (rg=tid&7, cl=tid>>3): rows 32rg..32rg+31 of column h*128+cl,
// 16 v2f row-pairs. Fused loop does update + sumA^4 + q-dot + next-k-dot
// in one pass; cross-rg reduces are xor{1,2,4} in-wave. Triple-buffered
// k/q/v/ea; 4-slot rotating LDS s4 accumulator (ds_add_f32 + counter,
// 16th wave publishes).
// k/q LDS tiles: 32-row blocks at stride RBS=36 words -> fused-loop float4
// reads hit bank-words 4rg+4j (distinct across rg) = conflict-free.
// ---------------------------------------------------------------------------
__global__ __launch_bounds__(1024, 4) void scan_kernel(
    const float* __restrict__ qn, const float* __restrict__ kn,
    const float* __restrict__ vn, const float* __restrict__ eta,
    const float* __restrict__ alpha, const float* __restrict__ W0,
    float* __restrict__ y, float* __restrict__ g_s4)
{
  const int blkid = blockIdx.x;       // 0..7
  const int b     = blkid >> 1;
  const int h     = blkid & 1;
  const int peerb = blkid ^ 1;
  const int tid = threadIdx.x;
  const int rg = tid & 7;             // 8 row groups x 32 rows
  const int cl = tid >> 3;            // local column 0..127
  const int cg = (h << 7) + cl;       // global column
  const int r0 = rg << 5;
  const int koff = rg * RBS;

  __shared__ float s_k[3][8*RBS], s_q[3][8*RBS], s_v[3][256];
  __shared__ float s_ea[3][2];
  __shared__ float s_acc[4];
  __shared__ unsigned s_cnt[4];

  // A2[2j]={A[r0+4j][cg],A[r0+4j+1][cg]}, A2[2j+1]={+2,+3}, j=0..7
  v2f A2[16];
  #pragma unroll
  for (int j=0;j<16;j++) A2[j] = (v2f)(0.f);

  const float* kb = kn + b*SEQT*DIMD;
  const float* qb = qn + b*SEQT*DIMD;
  const float* vb = vn + b*SEQT*DIMD;
  const float* eb = eta   + b*SEQT;
  const float* ab = alpha + b*SEQT;
  float* yb = y + b*SEQT*DIMD;

  if (tid < 4) { s_acc[tid] = 0.f; s_cnt[tid] = 0u; }

  // ---- prologue: stage t=0 -> buf0 (staggered k/q) ; load t=1 into pf
  if (tid < 64) {
    float4 v0 = ((const float4*)kb)[tid];
    *(float4*)&s_k[0][(tid>>3)*RBS + (tid&7)*4] = v0;
  } else if (tid < 128) {
    int i = tid-64;
    float4 v0 = ((const float4*)qb)[i];
    *(float4*)&s_q[0][(i>>3)*RBS + (i&7)*4] = v0;
  } else if (tid < 192) {
    ((float4*)s_v[0])[tid-128] = ((const float4*)vb)[tid-128];
  }
  if (tid == 192) { s_ea[0][0] = eb[0]; s_ea[0][1] = ab[0]; }

  float4 pf = make_float4(0.f,0.f,0.f,0.f);
  float pe = 0.f, pa = 0.f;
  if (tid < 64)       pf = ((const float4*)(kb + DIMD))[tid];
  else if (tid < 128) pf = ((const float4*)(qb + DIMD))[tid-64];
  else if (tid < 192) pf = ((const float4*)(vb + DIMD))[tid-128];
  if (tid == 192) { pe = eb[1]; pa = ab[1]; }
  __syncthreads();

  // ---- prologue: pred_raw(0) = k(0) . W0 over own rows, own column
  float pr = 0.f;
  {
    #pragma unroll 4
    for (int j=0;j<32;j++)
      pr = fmaf(s_k[0][koff + j], W0[(size_t)(r0+j)*DIMD + cg], pr);
    pr += __shfl_xor(pr, 1, 64);
    pr += __shfl_xor(pr, 2, 64);
    pr += __shfl_xor(pr, 4, 64);
  }

  float up = 0.f;
  int cur = 0;

  for (int t=0; t<SEQT; ++t) {
    const int nxt = (cur==2) ? 0 : cur+1;

    // ---- stage pf (t+1) -> buf nxt
    if (t+1 < SEQT) {
      if (tid < 64)       *(float4*)&s_k[nxt][(tid>>3)*RBS + (tid&7)*4] = pf;
      else if (tid < 128){ int i = tid-64; *(float4*)&s_q[nxt][(i>>3)*RBS + (i&7)*4] = pf; }
      else if (tid < 192) ((float4*)s_v[nxt])[tid-128] = pf;
      if (tid == 192) { s_ea[nxt][0]=pe; s_ea[nxt][1]=pa; }
    }

    __syncthreads();                               // the ONE barrier

    // rotate-zero the s4 slot that will be accumulated at step t+1
    if (tid == 256) { s_acc[(t+1)&3] = 0.f; s_cnt[(t+1)&3] = 0u; }

    // ---- issue global prefetch for t+2
    if (t+2 < SEQT) {
      if (tid < 64)       pf = ((const float4*)(kb + (t+2)*DIMD))[tid];
      else if (tid < 128) pf = ((const float4*)(qb + (t+2)*DIMD))[tid-64];
      else if (tid < 192) pf = ((const float4*)(vb + (t+2)*DIMD))[tid-128];
      if (tid == 192) { pe = eb[t+2]; pa = ab[t+2]; }
    }

    // ---- inv(t-1): own LDS partial + peer's published partial
    float scale = 1.f;
    if (t > 0) {
      float own = s_acc[(t-1)&3];
      const unsigned* pp = (const unsigned*)&g_s4[(size_t)(t-1)*8 + peerb];
      unsigned pv;
      do {
        pv = __hip_atomic_load(pp, __ATOMIC_ACQUIRE, __HIP_MEMORY_SCOPE_AGENT);
      } while (pv == 0xAAAAAAAAu);
      float s4t = own + __uint_as_float(pv);
      float w = sqrtf(s4t) + 1e-6f;
      float r = __builtin_amdgcn_rcpf(w);
      r = r * (2.f - w*r);          // Newton: feeds the recurrence
      scale = r;
      if (rg == 0) yb[(size_t)(t-1)*DIMD + cg] = up * r;
    }

    // ---- t0 for own column
    const float et = s_ea[cur][0], al = s_ea[cur][1];
    float pred = pr * scale;
    float df = pred - s_v[cur][cg];
    float e  = __expf(20.f*df);                    // tanh(10df)=1-2/(e+1)
    float th = 1.f - 2.f*__builtin_amdgcn_rcpf(e + 1.f);
    float t0 = et * 3.f * th * (df*df);
    v2f nt0; nt0.x = -t0; nt0.y = -t0;
    v2f alv; alv.x = al;  alv.y = al;

    // ---- fused: A update + sumA^4 + q-dot + NEXT k-dot (one pass)
    const float4* kp = (const float4*)(s_k[cur] + koff);
    const float4* qp = (const float4*)(s_q[cur] + koff);
    const float4* np = (const float4*)(s_k[nxt] + koff);   // k(t+1)
    v2f s4v = (v2f)(0.f), uv = (v2f)(0.f), pv2 = (v2f)(0.f);
    #pragma unroll
    for (int j=0;j<8;j++){
      float4 k4 = kp[j], q4 = qp[j], n4 = np[j];
      v2f klo = {k4.x,k4.y}, khi = {k4.z,k4.w};
      v2f qlo = {q4.x,q4.y}, qhi = {q4.z,q4.w};
      v2f nlo = {n4.x,n4.y}, nhi = {n4.z,n4.w};
      v2f a, sq;
      a = FMA2(alv, A2[2*j],   nt0*klo); A2[2*j]   = a;
      sq = a*a; s4v = FMA2(sq, sq, s4v);
      uv  = FMA2(qlo, a, uv);
      pv2 = FMA2(nlo, a, pv2);
      a = FMA2(alv, A2[2*j+1], nt0*khi); A2[2*j+1] = a;
      sq = a*a; s4v = FMA2(sq, sq, s4v);
      uv  = FMA2(qhi, a, uv);
      pv2 = FMA2(nhi, a, pv2);
    }

    // ---- cross-rg reduces (8 adjacent lanes share the column)
    float u = uv.x + uv.y;
    float p = pv2.x + pv2.y;
    u += __shfl_xor(u, 1, 64); p += __shfl_xor(p, 1, 64);
    u += __shfl_xor(u, 2, 64); p += __shfl_xor(p, 2, 64);
    u += __shfl_xor(u, 4, 64); p += __shfl_xor(p, 4, 64);
    up = u; pr = p;

    // ---- s4: wave reduce, LDS accumulate, 16th wave publishes
    float s4 = s4v.x + s4v.y;
    #pragma unroll
    for (int m=1;m<64;m<<=1) s4 += __shfl_xor(s4, m, 64);
    if ((tid & 63) == 0) {
      atomicAdd(&s_acc[t&3], s4);
      unsigned old = atomicAdd(&s_cnt[t&3], 1u);
      if (old == 15u) {
        float tot = s_acc[t&3];      // all 16 adds complete
        __hip_atomic_store((unsigned*)&g_s4[(size_t)t*8 + blkid],
                           __float_as_uint(tot),
                           __ATOMIC_RELEASE, __HIP_MEMORY_SCOPE_AGENT);
      }
    }

    cur = nxt;
  }

  __syncthreads();
  // epilogue: y for t = 1023
  {
    float own = s_acc[1023&3];
    const unsigned* pp = (const unsigned*)&g_s4[(size_t)1023*8 + peerb];
    unsigned pv;
    do {
      pv = __hip_atomic_load(pp, __ATOMIC_ACQUIRE, __HIP_MEMORY_SCOPE_AGENT);
    } while (pv == 0xAAAAAAAAu);
    float s4t = own + __uint_as_float(pv);
    float w = sqrtf(s4t) + 1e-6f;
    float r = __builtin_amdgcn_rcpf(w);
    r = r * (2.f - w*r);
    if (rg == 0) yb[(size_t)1023*DIMD + cg] = up * r;
  }
}

// ---------------------------------------------------------------------------
extern "C" void kernel_launch(void* const* d_in, const int* in_sizes, int n_in,
                              void* d_out, int out_size, void* d_ws, size_t ws_size,
                              hipStream_t stream)
{
  const float* x     = (const float*)d_in[0];
  const float* cosT  = (const float*)d_in[1];
  const float* sinT  = (const float*)d_in[2];
  const float* Wqkv  = (const float*)d_in[3];
  const float* qw    = (const float*)d_in[4];
  const float* qb    = (const float*)d_in[5];
  const float* kw    = (const float*)d_in[6];
  const float* kb    = (const float*)d_in[7];
  const float* vw    = (const float*)d_in[8];
  const float* vb    = (const float*)d_in[9];
  const float* Wparam= (const float*)d_in[10];
  const float* bparam= (const float*)d_in[11];
  const float* W0    = (const float*)d_in[12];
  const float* Wgate = (const float*)d_in[13];
  const float* Wout  = (const float*)d_in[14];
  float* out = (float*)d_out;

  float* ws    = (float*)d_ws;
  float* qkvr  = ws;                         // 4*1024*768  = 3,145,728 f
  float* qn    = qkvr + 4*1024*768;          // 1,048,576 f
  float* kn    = qn   + 4*1024*256;
  float* vn    = kn   + 4*1024*256;
  float* eta   = vn   + 4*1024*256;          // 4096 f
  float* alpha = eta  + 4096;                // 4096 f
  // qkvr is dead after prep_kernel -> reuse its space:
  float* yv    = qkvr;                       // scan output   (1,048,576 f)
  float* tmpg  = qkvr + 1048576;             // gate preact   (1,048,576 f)
  float* g_s4  = qkvr + 2097152;             // s4 exchange   (1024*8 f)

  // 1) qkv = x @ Wqkv.T          (4096 x 768)
  gemm_bt<0><<<dim3(64*12), 256, 0, stream>>>(x, Wqkv, qkvr, 768, nullptr);
  // 2) conv + rope + l2norm + eta/alpha   (qkvr consumed here)
  prep_kernel<<<dim3(4096), 256, 0, stream>>>(qkvr, x, cosT, sinT,
      qw, qb, kw, kb, vw, vb, Wparam, bparam, qn, kn, vn, eta, alpha);
  // 2b) poison the s4 exchange slots (graph-capturable; ordered before scan)
  hipMemsetAsync(g_s4, 0xAA, (size_t)SEQT*8*sizeof(float), stream);
  // 3) the sequential scan: 2 blocks per batch, cross-block s4 exchange
  scan_kernel<<<dim3(NB*2), 1024, 0, stream>>>(qn, kn, vn, eta, alpha, W0,
                                               yv, g_s4);
  // 4) gate preact = x @ Wgate.T (4096 x 256)
  gemm_bt<0><<<dim3(64*4), 256, 0, stream>>>(x, Wgate, tmpg, 256, nullptr);
  // 5) out = (y @ Wout.T) * sigmoid(gate)
  gemm_bt<1><<<dim3(64*4), 256, 0, stream>>>(yv, Wout, out, 256, tmpg);
}

// Round 10
// 3053.876 us; speedup vs baseline: 1.2801x; 1.0251x over previous
//
#include <hip/hip_runtime.h>

#define DIMD 256
#define SEQT 1024
#define NB   4
#define KSTRIDE 272   // 256 + 4-float stagger pad per 64-row block

typedef float v2f __attribute__((ext_vector_type(2)));
#define FMA2(a,b,c) __builtin_elementwise_fma((a),(b),(c))

__device__ __forceinline__ float sigmoidf_(float x){ return 1.0f/(1.0f+expf(-x)); }

// ---------------------------------------------------------------------------
// GEMM: C[m][n] = sum_k A[m][k] * B[n][k], K = 256 fixed, tiles 64x64.
// EPI==1: C *= sigmoid(gpre[m*N+n])
// ---------------------------------------------------------------------------
template<int EPI>
__global__ __launch_bounds__(256) void gemm_bt(const float* __restrict__ A,
    const float* __restrict__ Bm, float* __restrict__ C, int N,
    const float* __restrict__ gpre)
{
  __shared__ float sA[64][68];
  __shared__ float sB[64][68];
  const int nb = N >> 6;
  const int bm = blockIdx.x / nb, bn = blockIdx.x - bm*nb;
  const int m0 = bm << 6, n0 = bn << 6;
  const int tid = threadIdx.x;
  const int tr = tid >> 4, tc = tid & 15;
  float acc[4][4];
  #pragma unroll
  for (int i=0;i<4;i++)
    #pragma unroll
    for (int j=0;j<4;j++) acc[i][j]=0.f;

  for (int kc=0;kc<4;kc++){
    __syncthreads();
    for (int i=tid;i<1024;i+=256){
      int r = i >> 4, q4 = i & 15;
      *(float4*)&sA[r][q4*4] = ((const float4*)(A  + (m0+r)*256 + kc*64))[q4];
      *(float4*)&sB[r][q4*4] = ((const float4*)(Bm + (n0+r)*256 + kc*64))[q4];
    }
    __syncthreads();
    #pragma unroll
    for (int kq=0;kq<16;kq++){
      float4 av[4], bv[4];
      #pragma unroll
      for (int i=0;i<4;i++) av[i] = *(const float4*)&sA[tr+16*i][kq*4];
      #pragma unroll
      for (int j=0;j<4;j++) bv[j] = *(const float4*)&sB[tc+16*j][kq*4];
      #pragma unroll
      for (int i=0;i<4;i++)
        #pragma unroll
        for (int j=0;j<4;j++)
          acc[i][j] = fmaf(av[i].x,bv[j].x, fmaf(av[i].y,bv[j].y,
                      fmaf(av[i].z,bv[j].z, fmaf(av[i].w,bv[j].w, acc[i][j]))));
    }
  }
  #pragma unroll
  for (int i=0;i<4;i++){
    #pragma unroll
    for (int j=0;j<4;j++){
      int m = m0 + tr + 16*i, n = n0 + tc + 16*j;
      float val = acc[i][j];
      if (EPI==1) val *= sigmoidf_(gpre[m*N+n]);
      C[m*N+n] = val;
    }
  }
}

// ---------------------------------------------------------------------------
// prep: causal dwconv(4) + RoPE + l2norm for q,k ; conv for v ; eta/alpha.
// ---------------------------------------------------------------------------
__global__ __launch_bounds__(256) void prep_kernel(
    const float* __restrict__ qkvr, const float* __restrict__ x,
    const float* __restrict__ cosT, const float* __restrict__ sinT,
    const float* __restrict__ qw, const float* __restrict__ qbias,
    const float* __restrict__ kw, const float* __restrict__ kbias,
    const float* __restrict__ vw, const float* __restrict__ vbias,
    const float* __restrict__ Wparam, const float* __restrict__ bparam,
    float* __restrict__ qo, float* __restrict__ ko, float* __restrict__ vo,
    float* __restrict__ eo, float* __restrict__ ao)
{
  const int bt = blockIdx.x;
  const int t = bt & 1023;
  const int d = threadIdx.x;

  float4 wq = ((const float4*)qw)[d];
  float4 wk = ((const float4*)kw)[d];
  float4 wv = ((const float4*)vw)[d];
  const float wqj[4] = {wq.x,wq.y,wq.z,wq.w};
  const float wkj[4] = {wk.x,wk.y,wk.z,wk.w};
  const float wvj[4] = {wv.x,wv.y,wv.z,wv.w};
  float qa = qbias[d], ka = kbias[d], va = vbias[d];
  #pragma unroll
  for (int j=0;j<4;j++){
    int tt = t - 3 + j;
    if (tt >= 0) {
      const float* row = qkvr + (size_t)(bt - 3 + j) * 768;
      qa = fmaf(row[d],      wqj[j], qa);
      ka = fmaf(row[256+d],  wkj[j], ka);
      va = fmaf(row[512+d],  wvj[j], va);
    }
  }
  vo[bt*256 + d] = va;

  __shared__ float sq[256], sk[256];
  __shared__ float red[4][4];
  sq[d] = qa; sk[d] = ka;
  __syncthreads();
  const int i = d >> 1;
  const float c = cosT[t*128 + i], s = sinT[t*128 + i];
  float qr, krp;
  if ((d & 1) == 0) { qr = sq[d]*c - sq[d+1]*s;  krp = sk[d]*c - sk[d+1]*s; }
  else              { qr = sq[d-1]*s + sq[d]*c;  krp = sk[d-1]*s + sk[d]*c; }

  const float xd = x[bt*256 + d];
  float r0 = qr*qr, r1 = krp*krp, r2 = xd*Wparam[d], r3 = xd*Wparam[256+d];
  #pragma unroll
  for (int m=1;m<64;m<<=1){
    r0 += __shfl_xor(r0, m, 64);
    r1 += __shfl_xor(r1, m, 64);
    r2 += __shfl_xor(r2, m, 64);
    r3 += __shfl_xor(r3, m, 64);
  }
  const int w = d >> 6;
  if ((d & 63) == 0){ red[w][0]=r0; red[w][1]=r1; red[w][2]=r2; red[w][3]=r3; }
  __syncthreads();
  float qss = red[0][0]+red[1][0]+red[2][0]+red[3][0];
  float kss = red[0][1]+red[1][1]+red[2][1]+red[3][1];
  qo[bt*256+d] = qr  / fmaxf(sqrtf(qss), 1e-12f);
  ko[bt*256+d] = krp / fmaxf(sqrtf(kss), 1e-12f);
  if (d == 0){
    float p0 = red[0][2]+red[1][2]+red[2][2]+red[3][2] + bparam[0];
    float p1 = red[0][3]+red[1][3]+red[2][3]+red[3][3] + bparam[1];
    eo[bt] = 1.f/(1.f+expf(-p0));
    ao[bt] = 1.f/(1.f+expf(-p1));
  }
}

// ---------------------------------------------------------------------------
// scan: one block per batch, 1024 threads, ONE barrier per step.
// Thread (c=tid>>2, rg=tid&3) owns A[rg*64..rg*64+63][c] as 32 v2f regs.
// __launch_bounds__(1024, 2): 256-VGPR budget. Rationale: with (1024,4) the
// compiler targeted 64 arch-VGPRs (for 2-blocks/CU occupancy we never use,
// grid=NB=4) and parked A in AGPRs -- scalar VALU reads AGPRs fine, but
// VOP3P v_pk_fma_f32 cannot, so every packed-math attempt silently
// scalarized (R2/R3) or shuttled (R8). With the 256-reg budget A stays in
// arch VGPRs and FMA2 on v2f can select v_pk_fma_f32 (2 fp32 FLOP/slot).
// The 4 row-group partials of a column live in adjacent lanes -> pred and
// q-dot reduce via 2x __shfl_xor. Only scalar sumA^4 crosses waves,
// consumed one step later -> single barrier per step. k/q/v/ea triple-
// buffered; s_s4 double-buffered; k/q staggered (stride 68/row-block).
// ---------------------------------------------------------------------------
__global__ __launch_bounds__(1024, 2) void scan_kernel(
    const float* __restrict__ qn, const float* __restrict__ kn,
    const float* __restrict__ vn, const float* __restrict__ eta,
    const float* __restrict__ alpha, const float* __restrict__ W0,
    float* __restrict__ y)
{
  const int b = blockIdx.x;
  const int tid = threadIdx.x;
  const int rg = tid & 3;         // row group
  const int c  = tid >> 2;        // owned column
  const int r0 = rg << 6;         // first owned row
  const int koff = 68 * rg;       // staggered base of this row block

  __shared__ float s_k[3][KSTRIDE], s_q[3][KSTRIDE], s_v[3][256];
  __shared__ float s_ea[3][2];
  __shared__ float s_s4[2][16];

  v2f A2[32];
  #pragma unroll
  for (int j=0;j<32;j++) A2[j] = (v2f)(0.f);

  const float* kb = kn + b*SEQT*DIMD;
  const float* qb = qn + b*SEQT*DIMD;
  const float* vb = vn + b*SEQT*DIMD;
  const float* eb = eta   + b*SEQT;
  const float* ab = alpha + b*SEQT;
  float* yb = y + b*SEQT*DIMD;

  // prologue: stage t=0 into buf0 ; load t=1 into pf regs
  if (tid < 64) {
    float4 v0 = ((const float4*)kb)[tid];
    *(float4*)&s_k[0][4*tid + (tid>>4)*4] = v0;
  } else if (tid < 128) {
    int i = tid-64;
    float4 v0 = ((const float4*)qb)[i];
    *(float4*)&s_q[0][4*i + (i>>4)*4] = v0;
  } else if (tid < 192) {
    ((float4*)s_v[0])[tid-128] = ((const float4*)vb)[tid-128];
  }
  if (tid == 192) { s_ea[0][0] = eb[0]; s_ea[0][1] = ab[0]; }

  float4 pf = make_float4(0.f,0.f,0.f,0.f);
  float pe = 0.f, pa = 0.f;
  if (tid < 64)       pf = ((const float4*)(kb + DIMD))[tid];
  else if (tid < 128) pf = ((const float4*)(qb + DIMD))[tid-64];
  else if (tid < 192) pf = ((const float4*)(vb + DIMD))[tid-128];
  if (tid == 192) { pe = eb[1]; pa = ab[1]; }
  __syncthreads();

  float inv_prev = 1.0f;
  float u_prev = 0.f;
  int cur = 0;

  for (int t=0; t<SEQT; ++t) {
    const int nxt = (cur==2) ? 0 : cur+1;

    // ---- pre-phase: stage pf (t+1 data, loaded last post-phase) -> buf nxt
    if (t+1 < SEQT) {
      if (tid < 64)       *(float4*)&s_k[nxt][4*tid + (tid>>4)*4] = pf;
      else if (tid < 128){ int i = tid-64; *(float4*)&s_q[nxt][4*i + (i>>4)*4] = pf; }
      else if (tid < 192) ((float4*)s_v[nxt])[tid-128] = pf;
      if (tid == 192) { s_ea[nxt][0]=pe; s_ea[nxt][1]=pa; }
    }

    // ---- k-dot partial over owned rows (packed)
    float pred_raw;
    if (t == 0) {
      const float* w0p = W0 + (size_t)r0*DIMD + c;
      const float* kq = s_k[0] + koff;
      float acc = 0.f;
      #pragma unroll
      for (int j=0;j<64;j++)
        acc = fmaf(kq[j], w0p[(size_t)j*DIMD], acc);
      pred_raw = acc;
    } else {
      const float4* kp = (const float4*)(s_k[cur] + koff);
      v2f acc0 = (v2f)(0.f), acc1 = (v2f)(0.f);
      #pragma unroll
      for (int jq=0;jq<16;jq++){
        float4 kv = kp[jq];
        v2f klo = {kv.x, kv.y}, khi = {kv.z, kv.w};
        acc0 = FMA2(klo, A2[2*jq],   acc0);
        acc1 = FMA2(khi, A2[2*jq+1], acc1);
      }
      pred_raw = (acc0.x + acc0.y) + (acc1.x + acc1.y);
    }
    // in-wave cross-rg reduce (lanes ^1, ^2 share the column)
    pred_raw += __shfl_xor(pred_raw, 1, 64);
    pred_raw += __shfl_xor(pred_raw, 2, 64);

    __syncthreads();                                   // the ONE barrier

    // ---- post-phase
    // issue prefetch for t+2 (lands during fused loop; staged next pre-phase)
    if (t+2 < SEQT) {
      if (tid < 64)       pf = ((const float4*)(kb + (t+2)*DIMD))[tid];
      else if (tid < 128) pf = ((const float4*)(qb + (t+2)*DIMD))[tid-64];
      else if (tid < 192) pf = ((const float4*)(vb + (t+2)*DIMD))[tid-128];
      if (tid == 192) { pe = eb[t+2]; pa = ab[t+2]; }
    }

    // inv from previous step's sumA^4 ; deferred y-write for t-1
    if (t > 0) {
      const float* sp = s_s4[(t-1)&1];
      float4 sa = ((const float4*)sp)[0], sb4 = ((const float4*)sp)[1];
      float4 sc4= ((const float4*)sp)[2], sd4 = ((const float4*)sp)[3];
      float s4t = ((sa.x+sa.y)+(sa.z+sa.w)) + ((sb4.x+sb4.y)+(sb4.z+sb4.w))
                + ((sc4.x+sc4.y)+(sc4.z+sc4.w)) + ((sd4.x+sd4.y)+(sd4.z+sd4.w));
      float w = sqrtf(s4t) + 1e-6f;
      float r = __builtin_amdgcn_rcpf(w);
      r = r * (2.f - w*r);          // Newton: feeds the recurrence
      inv_prev = r;
      if (rg == 0) yb[(t-1)*DIMD + c] = u_prev * r;
    }

    float pred = pred_raw * inv_prev;
    const float et = s_ea[cur][0], al = s_ea[cur][1];
    float df = pred - s_v[cur][c];
    // tanh(10*df) = 1 - 2/(exp(20*df)+1)
    float e  = __expf(20.f*df);
    float th = 1.f - 2.f*__builtin_amdgcn_rcpf(e + 1.f);
    float t0 = et * 3.f * th * (df*df);

    // fused: A update + sumA^4 partial + q-dot on new A (packed)
    const v2f alv = {al, al};
    const v2f nt0 = {-t0, -t0};
    v2f s4a = (v2f)(0.f), s4b = (v2f)(0.f);
    v2f u2a = (v2f)(0.f), u2b = (v2f)(0.f);
    {
      const float4* kp = (const float4*)(s_k[cur] + koff);
      const float4* qp = (const float4*)(s_q[cur] + koff);
      #pragma unroll
      for (int jq=0;jq<16;jq++){
        float4 kv = kp[jq], qv = qp[jq];
        v2f klo = {kv.x, kv.y}, khi = {kv.z, kv.w};
        v2f qlo = {qv.x, qv.y}, qhi = {qv.z, qv.w};
        v2f a, a2;
        a = FMA2(alv, A2[2*jq],   nt0*klo); A2[2*jq]   = a;
        a2 = a*a; s4a = FMA2(a2, a2, s4a);  u2a = FMA2(qlo, a, u2a);
        a = FMA2(alv, A2[2*jq+1], nt0*khi); A2[2*jq+1] = a;
        a2 = a*a; s4b = FMA2(a2, a2, s4b);  u2b = FMA2(qhi, a, u2b);
      }
    }
    float u = (u2a.x + u2a.y) + (u2b.x + u2b.y);
    u += __shfl_xor(u, 1, 64);
    u += __shfl_xor(u, 2, 64);
    u_prev = u;

    float s4 = (s4a.x + s4a.y) + (s4b.x + s4b.y);
    #pragma unroll
    for (int m=1;m<64;m<<=1) s4 += __shfl_xor(s4, m, 64);
    if ((tid & 63) == 0) s_s4[t&1][tid>>6] = s4;

    cur = nxt;
  }

  __syncthreads();
  // epilogue: y for t = 1023 (s4 sits in s_s4[1023&1 = 1])
  {
    const float* sp = s_s4[1];
    float4 sa = ((const float4*)sp)[0], sb4 = ((const float4*)sp)[1];
    float4 sc4= ((const float4*)sp)[2], sd4 = ((const float4*)sp)[3];
    float s4t = ((sa.x+sa.y)+(sa.z+sa.w)) + ((sb4.x+sb4.y)+(sb4.z+sb4.w))
              + ((sc4.x+sc4.y)+(sc4.z+sc4.w)) + ((sd4.x+sd4.y)+(sd4.z+sd4.w));
    float w = sqrtf(s4t) + 1e-6f;
    float r = __builtin_amdgcn_rcpf(w);
    r = r * (2.f - w*r);
    if (rg == 0) yb[1023*DIMD + c] = u_prev * r;
  }
}

// ---------------------------------------------------------------------------
extern "C" void kernel_launch(void* const* d_in, const int* in_sizes, int n_in,
                              void* d_out, int out_size, void* d_ws, size_t ws_size,
                              hipStream_t stream)
{
  const float* x     = (const float*)d_in[0];
  const float* cosT  = (const float*)d_in[1];
  const float* sinT  = (const float*)d_in[2];
  const float* Wqkv  = (const float*)d_in[3];
  const float* qw    = (const float*)d_in[4];
  const float* qb    = (const float*)d_in[5];
  const float* kw    = (const float*)d_in[6];
  const float* kb    = (const float*)d_in[7];
  const float* vw    = (const float*)d_in[8];
  const float* vb    = (const float*)d_in[9];
  const float* Wparam= (const float*)d_in[10];
  const float* bparam= (const float*)d_in[11];
  const float* W0    = (const float*)d_in[12];
  const float* Wgate = (const float*)d_in[13];
  const float* Wout  = (const float*)d_in[14];
  float* out = (float*)d_out;

  float* ws    = (float*)d_ws;
  float* qkvr  = ws;                         // 4*1024*768  = 3,145,728 f
  float* qn    = qkvr + 4*1024*768;          // 1,048,576 f
  float* kn    = qn   + 4*1024*256;
  float* vn    = kn   + 4*1024*256;
  float* eta   = vn   + 4*1024*256;          // 4096 f
  float* alpha = eta  + 4096;                // 4096 f
  // qkvr is dead after prep_kernel -> reuse its space:
  float* yv    = qkvr;                       // scan output  (1,048,576 f)
  float* tmpg  = qkvr + 1048576;             // gate preact  (1,048,576 f)

  // 1) qkv = x @ Wqkv.T          (4096 x 768)
  gemm_bt<0><<<dim3(64*12), 256, 0, stream>>>(x, Wqkv, qkvr, 768, nullptr);
  // 2) conv + rope + l2norm + eta/alpha
  prep_kernel<<<dim3(4096), 256, 0, stream>>>(qkvr, x, cosT, sinT,
      qw, qb, kw, kb, vw, vb, Wparam, bparam, qn, kn, vn, eta, alpha);
  // 3) the sequential scan (one block per batch)
  scan_kernel<<<dim3(NB), 1024, 0, stream>>>(qn, kn, vn, eta, alpha, W0, yv);
  // 4) gate preact = x @ Wgate.T (4096 x 256)
  gemm_bt<0><<<dim3(64*4), 256, 0, stream>>>(x, Wgate, tmpg, 256, nullptr);
  // 5) out = (y @ Wout.T) * sigmoid(gate)
  gemm_bt<1><<<dim3(64*4), 256, 0, stream>>>(yv, Wout, out, 256, tmpg);
}